// Round 2
// baseline (1075.313 us; speedup 1.0000x reference)
//
#include <hip/hip_runtime.h>
#include <hip/hip_bf16.h>

#define NN 204800      // nodes
#define EE 1638400     // edges
#define BBATCH 4096    // graphs
#define NPGRAPH 50
#define KTOP 10
#define NBLK 200       // scan blocks (NN / 1024)

// converted-weight offsets (floats) inside wconv region
#define OFF_W1  0
#define OFF_W2  8192
#define OFF_W3  12288
#define OFF_B1  16384
#define OFF_B2  16448
#define OFF_B3  16512
#define OFF_WC1 16576
#define OFF_BC1 17856
#define OFF_WC2 17888
#define OFF_BC2 24032
#define OFF_WF  24096
#define OFF_BF  24736
#define WTOT    24746

typedef __bf16 bf16x8 __attribute__((ext_vector_type(8)));
typedef float  f32x4  __attribute__((ext_vector_type(4)));

__device__ __forceinline__ float bf2f(unsigned short u) {
    unsigned int x = ((unsigned int)u) << 16;
    float f; __builtin_memcpy(&f, &x, 4); return f;
}

// pack (src, coef) into one 8B record: one dirtied line per edge, not two
__device__ __forceinline__ long long pack_sc(int s, float c) {
    return ((long long)(unsigned)__float_as_int(c) << 32) | (unsigned)s;
}

// ---------------- dtype detection ----------------
// flags[0]: 1 if float tensors are fp32, 0 if bf16
// flags[1]: 1 if edge_index is int64, 0 if int32
__global__ void detect_kernel(const unsigned int* __restrict__ xw,
                              const unsigned int* __restrict__ eiw,
                              int* __restrict__ flags) {
    __shared__ int s_f32, s_i64;
    int t = threadIdx.x;
    if (t == 0) { s_f32 = 0; s_i64 = 1; }
    __syncthreads();
    unsigned w = xw[t];                       // 256 words = 512 ushorts of x
    unsigned u0 = w & 0xffffu, u1 = w >> 16;
    int e0 = (u0 >> 7) & 0xff, e1 = (u1 >> 7) & 0xff;
    // genuine bf16 N(0,1) never reaches |v| >= 512 (exp >= 0x88)
    if (e0 >= 0x88 || e1 >= 0x88) atomicOr(&s_f32, 1);
    // int64 indices < 2^31: high word of every packed pair is 0
    if (eiw[2 * t + 1] != 0) atomicAnd(&s_i64, 0);
    __syncthreads();
    if (t == 0) { flags[0] = s_f32; flags[1] = s_i64; }
}

// ---------------- weights convert (bf16 or fp32 -> fp32) ----------------

struct WPtrs { const void* p[12]; };

__global__ void convert_weights_kernel(WPtrs wp, const int* __restrict__ flags,
                                       float* __restrict__ dst) {
    const int lens[12] = {8192,4096,4096,64,64,64,1280,32,6144,64,640,10};
    const int offs[12] = {OFF_W1,OFF_W2,OFF_W3,OFF_B1,OFF_B2,OFF_B3,
                          OFF_WC1,OFF_BC1,OFF_WC2,OFF_BC2,OFF_WF,OFF_BF};
    int f32 = flags[0];
    int t = blockIdx.x * 256 + threadIdx.x;
    for (int s = 0; s < 12; ++s) {
        if (t < lens[s]) {
            float v = f32 ? ((const float*)wp.p[s])[t]
                          : bf2f(((const unsigned short*)wp.p[s])[t]);
            dst[offs[s] + t] = v;
            return;
        }
        t -= lens[s];
    }
}

// ---------------- transposed bf16 weights for MFMA path ----------------
// wt layout: [0,8192) Wt1 = W1^T (64 cols x 128 k)
//            [8192,12288) Wt2 = W2^T (64 x 64)
//            [12288,16384) Wt3 = W3^T (64 x 64)
__global__ void prep_wt_kernel(const float* __restrict__ wconv,
                               __bf16* __restrict__ wt) {
    int i = blockIdx.x * 256 + threadIdx.x;
    if (i < 8192) {
        int c = i >> 7, k = i & 127;
        wt[i] = (__bf16)wconv[OFF_W1 + k * 64 + c];
    } else if (i < 12288) {
        int j = i - 8192; int c = j >> 6, k = j & 63;
        wt[i] = (__bf16)wconv[OFF_W2 + k * 64 + c];
    } else if (i < 16384) {
        int j = i - 12288; int c = j >> 6, k = j & 63;
        wt[i] = (__bf16)wconv[OFF_W3 + k * 64 + c];
    }
}

// ---------------- CSR build ----------------

__global__ void zero_int_kernel(int* p, int n) {
    int i = blockIdx.x * 256 + threadIdx.x;
    if (i < n) p[i] = 0;
}

__device__ __forceinline__ int ld_idx(const void* ei, int i64, long pos) {
    return i64 ? (int)((const long long*)ei)[pos] : ((const int*)ei)[pos];
}

__global__ void count_kernel(const void* __restrict__ ei, const int* __restrict__ flags,
                             int* __restrict__ cnt) {
    int e = blockIdx.x * 256 + threadIdx.x;
    if (e >= EE) return;
    int c = ld_idx(ei, flags[1], (long)EE + e);
    atomicAdd(&cnt[c], 1);
}

// pass 1: block-local exclusive scan of (cnt[i]+1); per-block totals; dinv
__global__ __launch_bounds__(1024) void scan1_kernel(const int* __restrict__ cnt,
                                                     int* __restrict__ offs,
                                                     float* __restrict__ dinv,
                                                     int* __restrict__ blksum) {
    __shared__ int wsum[16];
    int b = blockIdx.x, t = threadIdx.x;
    int lane = t & 63, wid = t >> 6;
    int i = b * 1024 + t;
    int v = cnt[i] + 1;
    int x = v;
    #pragma unroll
    for (int d = 1; d < 64; d <<= 1) { int y = __shfl_up(x, d, 64); if (lane >= d) x += y; }
    if (lane == 63) wsum[wid] = x;
    __syncthreads();
    if (t == 0) {
        int run = 0;
        #pragma unroll
        for (int k = 0; k < 16; ++k) { int tmp = wsum[k]; wsum[k] = run; run += tmp; }
        blksum[b] = run;
    }
    __syncthreads();
    offs[i] = wsum[wid] + x - v;                 // block-local exclusive
    dinv[i] = (float)(1.0 / sqrt((double)v));    // deg = indeg + 1
}

// pass 2: exclusive scan of the 200 block sums (single block)
__global__ __launch_bounds__(256) void scan2_kernel(int* __restrict__ blksum) {
    __shared__ int wsum[4];
    int t = threadIdx.x, lane = t & 63, wid = t >> 6;
    int v = (t < NBLK) ? blksum[t] : 0;
    int x = v;
    #pragma unroll
    for (int d = 1; d < 64; d <<= 1) { int y = __shfl_up(x, d, 64); if (lane >= d) x += y; }
    if (lane == 63) wsum[wid] = x;
    __syncthreads();
    int pre = 0;
    for (int k = 0; k < wid; ++k) pre += wsum[k];
    if (t < NBLK) blksum[t] = pre + x - v;       // exclusive
}

// pass 3: add block offsets; write sentinel
__global__ __launch_bounds__(1024) void scan3_kernel(int* __restrict__ offs,
                                                     const int* __restrict__ blksum) {
    int b = blockIdx.x, i = b * 1024 + threadIdx.x;
    offs[i] += blksum[b];
    if (i == 0) offs[NN] = EE + NN;
}

__global__ void fill_self_kernel(const int* __restrict__ offs, const float* __restrict__ dinv,
                                 int* __restrict__ cursor, long long* __restrict__ epack) {
    int n = blockIdx.x * 256 + threadIdx.x;
    if (n >= NN) return;
    int p = offs[n];
    float d = dinv[n];
    __builtin_nontemporal_store(pack_sc(n, d * d), &epack[p]);
    cursor[n] = 1;
}

__global__ void fill_edges_kernel(const void* __restrict__ ei, const int* __restrict__ flags,
                                  const int* __restrict__ offs,
                                  const float* __restrict__ dinv, int* __restrict__ cursor,
                                  long long* __restrict__ epack) {
    int e = blockIdx.x * 256 + threadIdx.x;
    if (e >= EE) return;
    int i64 = flags[1];
    int r = ld_idx(ei, i64, e);
    int c = ld_idx(ei, i64, (long)EE + e);
    int p = offs[c] + atomicAdd(&cursor[c], 1);
    __builtin_nontemporal_store(pack_sc(r, dinv[r] * dinv[c]), &epack[p]);
}

// ---------------- MFMA XW (bf16 path): h = A @ W ----------------
// MODE 1: A is bf16 rows of 128 (layer 1), K=128, exact bf16 products.
// MODE 0: A is fp32 (row_stride floats, col_off), K=64, exact hi/lo split:
//         v = hi + lo (both bf16), v*w = hi*w + lo*w since w is exactly bf16.
// Block = 4 waves x 16 rows, 4 tiles per block -> grid 800.
// No LDS, no barriers: A-frag 16B/lane direct global loads, B hoisted in VGPRs.

template<int MODE>
__global__ __launch_bounds__(256) void xw_mfma_kernel(const void* __restrict__ A_,
                                                      const int* __restrict__ flags,
                                                      int row_stride, int col_off,
                                                      const __bf16* __restrict__ Wt,
                                                      float* __restrict__ hout) {
    if (flags[0] != 0) return;          // fp32 input -> fallback kernel handles
    constexpr int KW = (MODE == 1) ? 128 : 64;
    const int L = threadIdx.x & 63;
    const int w = threadIdx.x >> 6;
    const int rsub = L & 15;            // row-in-tile (A) / col-in-tile (B,C)
    const int ko = (L >> 4) * 8;        // k-offset of this lane's fragment

    // hoist all B fragments: Wt[c][k], frag = 8 consecutive k at col ct*16+rsub
    bf16x8 bfrag[4][KW / 32];
    #pragma unroll
    for (int ct = 0; ct < 4; ++ct)
        #pragma unroll
        for (int kb = 0; kb < KW / 32; ++kb)
            bfrag[ct][kb] = *reinterpret_cast<const bf16x8*>(
                Wt + (ct * 16 + rsub) * KW + kb * 32 + ko);

    #pragma unroll 1
    for (int it = 0; it < 4; ++it) {
        long row0 = ((long)blockIdx.x * 4 + it) * 64 + w * 16;
        long r = row0 + rsub;
        f32x4 acc[4] = {{0.f,0.f,0.f,0.f},{0.f,0.f,0.f,0.f},
                        {0.f,0.f,0.f,0.f},{0.f,0.f,0.f,0.f}};

        if (MODE == 1) {
            const __bf16* ap = (const __bf16*)A_ + r * 128;
            bf16x8 afr[4];
            #pragma unroll
            for (int kb = 0; kb < 4; ++kb)
                afr[kb] = *reinterpret_cast<const bf16x8*>(ap + kb * 32 + ko);
            #pragma unroll
            for (int kb = 0; kb < 4; ++kb)
                #pragma unroll
                for (int ct = 0; ct < 4; ++ct)
                    acc[ct] = __builtin_amdgcn_mfma_f32_16x16x32_bf16(
                        afr[kb], bfrag[ct][kb], acc[ct], 0, 0, 0);
        } else {
            const float* ap = (const float*)A_ + r * row_stride + col_off;
            f32x4 v[2][2];
            #pragma unroll
            for (int kb = 0; kb < 2; ++kb) {
                v[kb][0] = *reinterpret_cast<const f32x4*>(ap + kb * 32 + ko);
                v[kb][1] = *reinterpret_cast<const f32x4*>(ap + kb * 32 + ko + 4);
            }
            #pragma unroll
            for (int kb = 0; kb < 2; ++kb) {
                bf16x8 ah, al;
                #pragma unroll
                for (int e = 0; e < 8; ++e) {
                    float x = v[kb][e >> 2][e & 3];
                    __bf16 hi = (__bf16)x;
                    ah[e] = hi;
                    al[e] = (__bf16)(x - (float)hi);
                }
                #pragma unroll
                for (int ct = 0; ct < 4; ++ct) {
                    acc[ct] = __builtin_amdgcn_mfma_f32_16x16x32_bf16(
                        ah, bfrag[ct][kb], acc[ct], 0, 0, 0);
                    acc[ct] = __builtin_amdgcn_mfma_f32_16x16x32_bf16(
                        al, bfrag[ct][kb], acc[ct], 0, 0, 0);
                }
            }
        }
        // C layout: col = lane&15, row = (lane>>4)*4 + j
        float* hp = hout + row0 * 64;
        #pragma unroll
        for (int ct = 0; ct < 4; ++ct)
            #pragma unroll
            for (int j = 0; j < 4; ++j)
                hp[((L >> 4) * 4 + j) * 64 + ct * 16 + rsub] = acc[ct][j];
    }
}

// ---------------- dense XW (fp32 fallback path only) ----------------

template<int KD, int MODE>
__global__ __launch_bounds__(256) void xw_kernel(const void* __restrict__ xin_,
                                                 const int* __restrict__ flags,
                                                 int row_stride, int col_off,
                                                 const float* __restrict__ W,
                                                 float* __restrict__ hout) {
    if (flags[0] == 0) return;          // bf16 path handled by xw_mfma_kernel
    constexpr int CH = 32;
    __shared__ float xs[256 * 36];
    int t = threadIdx.x;
    long row0 = (long)blockIdx.x * 256;
    bool bf16in = (MODE == 1) && (flags[0] == 0);
    float acc[64];
    #pragma unroll
    for (int c = 0; c < 64; ++c) acc[c] = 0.f;

    for (int kb = 0; kb < KD; kb += CH) {
        __syncthreads();
        if (bf16in) {
            const unsigned short* x = (const unsigned short*)xin_;
            unsigned short* xsh = (unsigned short*)xs;
            #pragma unroll
            for (int rr = 0; rr < 32; ++rr) {
                int idx = rr * 256 + t;
                int r = idx >> 5, k = idx & 31;
                xsh[r * 40 + k] = x[(row0 + r) * row_stride + col_off + kb + k];
            }
        } else {
            const float* x = (const float*)xin_;
            #pragma unroll
            for (int rr = 0; rr < 32; ++rr) {
                int idx = rr * 256 + t;
                int r = idx >> 5, k = idx & 31;
                xs[r * 36 + k] = x[(row0 + r) * row_stride + col_off + kb + k];
            }
        }
        __syncthreads();
        if (bf16in) {
            #pragma unroll 2
            for (int k = 0; k < CH; ++k) {
                float xk = bf2f(((unsigned short*)xs)[t * 40 + k]);
                const float* wr = W + (kb + k) * 64;
                #pragma unroll
                for (int c = 0; c < 64; ++c) acc[c] = fmaf(xk, wr[c], acc[c]);
            }
        } else {
            #pragma unroll 2
            for (int k = 0; k < CH; ++k) {
                float xk = xs[t * 36 + k];
                const float* wr = W + (kb + k) * 64;
                #pragma unroll
                for (int c = 0; c < 64; ++c) acc[c] = fmaf(xk, wr[c], acc[c]);
            }
        }
    }
    float* o = hout + (row0 + t) * 64;
    #pragma unroll
    for (int c = 0; c < 64; c += 4) {
        float4 v; v.x = acc[c]; v.y = acc[c+1]; v.z = acc[c+2]; v.w = acc[c+3];
        *(float4*)(o + c) = v;
    }
}

// ---------------- SpMM (+self) + bias + tanh + per-layer key max ----------------
// one wave per node; lane = feature.

__global__ __launch_bounds__(256) void spmm_kernel(const float* __restrict__ h,
                                                   const int* __restrict__ offs,
                                                   const long long* __restrict__ epack,
                                                   const float* __restrict__ bias,
                                                   float* __restrict__ featOut,
                                                   float* __restrict__ keyOut) {
    int node = blockIdx.x * 4 + (threadIdx.x >> 6);
    int lane = threadIdx.x & 63;
    int j0 = offs[node], j1 = offs[node + 1];
    float acc = 0.f;

    for (int base = j0; base < j1; base += 64) {
        int n = j1 - base; if (n > 64) n = 64;
        long long my = 0;
        if (lane < n) my = epack[base + lane];   // coalesced 512B wave load

        int m = 0;
        for (; m + 8 <= n; m += 8) {
            float hv[8], cf[8];
            #pragma unroll
            for (int u = 0; u < 8; ++u) {
                long long e = __shfl(my, m + u, 64);
                int s = (int)(unsigned)e;
                cf[u] = __int_as_float((int)(e >> 32));
                hv[u] = h[(long)s * 64 + lane];
            }
            #pragma unroll
            for (int u = 0; u < 8; ++u) acc = fmaf(hv[u], cf[u], acc);
        }
        for (; m < n; ++m) {
            long long e = __shfl(my, m, 64);
            int s = (int)(unsigned)e;
            float cf = __int_as_float((int)(e >> 32));
            acc = fmaf(h[(long)s * 64 + lane], cf, acc);
        }
    }

    float val = tanhf(acc + bias[lane]);
    featOut[(long)node * 192 + lane] = val;
    float m = val;
    #pragma unroll
    for (int d = 32; d; d >>= 1) m = fmaxf(m, __shfl_xor(m, d, 64));
    if (lane == 0) keyOut[node] = m;
}

// ---------------- top-k selection per graph (key desc, index asc) ----------------

__global__ __launch_bounds__(256) void select_topk_kernel(const float* __restrict__ key3,
                                                          int* __restrict__ topidx) {
    int g = blockIdx.x * 4 + (threadIdx.x >> 6);
    int lane = threadIdx.x & 63;
    int node = g * NPGRAPH + lane;
    float k = -INFINITY;
    if (lane < NPGRAPH)
        k = fmaxf(fmaxf(key3[node], key3[NN + node]), key3[2 * NN + node]);
    for (int r = 0; r < KTOP; ++r) {
        float bk = k; int bi = lane;
        #pragma unroll
        for (int d = 32; d; d >>= 1) {
            float ok = __shfl_xor(bk, d, 64);
            int   oi = __shfl_xor(bi, d, 64);
            if (ok > bk || (ok == bk && oi < bi)) { bk = ok; bi = oi; }
        }
        if (lane == 0) topidx[g * KTOP + r] = g * NPGRAPH + bi;
        if (lane == bi) k = -INFINITY;
    }
}

// ---------------- gather + bitonic sort (values only) ----------------

__global__ __launch_bounds__(256) void sort_gather_kernel(const float* __restrict__ feat,
                                                          const int* __restrict__ topidx,
                                                          float* __restrict__ pooled) {
    int lane = threadIdx.x & 63;
    int w = threadIdx.x >> 6;
    int slot = blockIdx.x * 4 + w;
    int node = topidx[slot];

    unsigned v[4];
    #pragma unroll
    for (int t = 0; t < 3; ++t) {
        float x = feat[(long)node * 192 + 64 * t + lane];
        unsigned u = __float_as_uint(x);
        v[t] = (u & 0x80000000u) ? ~u : (u | 0x80000000u);   // order-preserving key
    }
    v[3] = 0xFF800000u;   // key(+inf) pad

    // bitonic sort, element index e = 64*t + lane, ascending
    #pragma unroll
    for (int k = 2; k <= 256; k <<= 1) {
        #pragma unroll
        for (int d = 128; d >= 1; d >>= 1) {
            if (d >= k) continue;           // folds at compile time
            if (d >= 64) {
                int dt = d >> 6;
                #pragma unroll
                for (int t = 0; t < 4; ++t) {
                    if (!(t & dt)) {
                        int t2 = t | dt;
                        bool asc = ((64 * t) & k) == 0;
                        unsigned a = v[t], b = v[t2];
                        unsigned mn = a < b ? a : b;
                        unsigned mx = a < b ? b : a;
                        v[t]  = asc ? mn : mx;
                        v[t2] = asc ? mx : mn;
                    }
                }
            } else {
                #pragma unroll
                for (int t = 0; t < 4; ++t) {
                    unsigned p = (unsigned)__shfl_xor((int)v[t], d, 64);
                    int e = 64 * t + lane;
                    bool lower = (lane & d) == 0;
                    bool asc = (e & k) == 0;
                    unsigned mn = v[t] < p ? v[t] : p;
                    unsigned mx = v[t] < p ? p : v[t];
                    v[t] = (lower == asc) ? mn : mx;
                }
            }
        }
    }

    #pragma unroll
    for (int t = 0; t < 3; ++t) {
        unsigned kk = v[t];
        unsigned u = (kk & 0x80000000u) ? (kk ^ 0x80000000u) : ~kk;
        pooled[(long)slot * 192 + 64 * t + lane] = __uint_as_float(u);
    }
}

// ---------------- conv1 + relu + maxpool ----------------

__global__ __launch_bounds__(256) void conv1_kernel(const float* __restrict__ pooled,
                                                    const float* __restrict__ wc,
                                                    float* __restrict__ pool1) {
    __shared__ float p[1920];    // [10][192]
    __shared__ float w[1280];    // [32][10][4]
    __shared__ float c1[1536];   // [32][48]
    int b = blockIdx.x, t = threadIdx.x;
    for (int i = t; i < 1920; i += 256) p[i] = pooled[(long)b * 1920 + i];
    for (int i = t; i < 1280; i += 256) w[i] = wc[OFF_WC1 + i];
    __syncthreads();
    for (int o = t; o < 1536; o += 256) {
        int oc = o / 48, s = o % 48;
        float acc = wc[OFF_BC1 + oc];
        #pragma unroll
        for (int ic = 0; ic < 10; ++ic)
            #pragma unroll
            for (int t4 = 0; t4 < 4; ++t4)
                acc = fmaf(p[ic * 192 + s * 4 + t4], w[oc * 40 + ic * 4 + t4], acc);
        c1[o] = fmaxf(acc, 0.f);
    }
    __syncthreads();
    for (int o = t; o < 384; o += 256) {
        int oc = o / 12, q = o % 12;
        float m = c1[oc * 48 + q * 4];
        #pragma unroll
        for (int u = 1; u < 4; ++u) m = fmaxf(m, c1[oc * 48 + q * 4 + u]);
        pool1[(long)b * 384 + o] = m;
    }
}

// ---------------- conv2 + relu + maxpool + FC; out dtype per flags[0] ----------------

__global__ __launch_bounds__(256) void conv2_fc_kernel(const float* __restrict__ pool1,
                                                       const float* __restrict__ wc,
                                                       const int* __restrict__ flags,
                                                       void* __restrict__ outv) {
    __shared__ float p[384];     // [32][12]
    __shared__ float w2[6144];   // [64][32][3]
    __shared__ float r2[256];    // [64][4]
    __shared__ float xfs[64];
    int b = blockIdx.x, t = threadIdx.x;
    int f32o = flags[0];
    for (int i = t; i < 384; i += 256) p[i] = pool1[(long)b * 384 + i];
    for (int i = t; i < 6144; i += 256) w2[i] = wc[OFF_WC2 + i];
    __syncthreads();
    {
        int oc = t >> 2, s = t & 3;
        float acc = wc[OFF_BC2 + oc];
        #pragma unroll
        for (int ic = 0; ic < 32; ++ic)
            #pragma unroll
            for (int t3 = 0; t3 < 3; ++t3)
                acc = fmaf(p[ic * 12 + 3 * s + t3], w2[oc * 96 + ic * 3 + t3], acc);
        r2[t] = fmaxf(acc, 0.f);
    }
    __syncthreads();
    if (t < 64) {
        float m = fmaxf(fmaxf(r2[4*t], r2[4*t+1]), fmaxf(r2[4*t+2], r2[4*t+3]));
        xfs[t] = m;
        long idx = (long)BBATCH * 10 + (long)b * 64 + t;
        if (f32o) ((float*)outv)[idx] = m;
        else      ((__hip_bfloat16*)outv)[idx] = __float2bfloat16(m);
    }
    __syncthreads();
    if (t < 10) {
        float acc = wc[OFF_BF + t];
        #pragma unroll
        for (int o = 0; o < 64; ++o)
            acc = fmaf(fmaxf(xfs[o], 0.f), wc[OFF_WF + o * 10 + t], acc);
        long idx = (long)b * 10 + t;
        if (f32o) ((float*)outv)[idx] = acc;
        else      ((__hip_bfloat16*)outv)[idx] = __float2bfloat16(acc);
    }
}

// ---------------- host ----------------

extern "C" void kernel_launch(void* const* d_in, const int* in_sizes, int n_in,
                              void* d_out, int out_size, void* d_ws, size_t ws_size,
                              hipStream_t stream) {
    const void* x  = d_in[0];   // [N,128] bf16 or fp32 (detected)
    const void* ei = d_in[1];   // [2,E] int32 or int64 (detected)
    // d_in[2] = batch (structure implied, unused)
    WPtrs wp;
    wp.p[0] = d_in[3];   // W1
    wp.p[1] = d_in[5];   // W2
    wp.p[2] = d_in[7];   // W3
    wp.p[3] = d_in[4];   // b1
    wp.p[4] = d_in[6];   // b2
    wp.p[5] = d_in[8];   // b3
    wp.p[6] = d_in[9];   // Wc1
    wp.p[7] = d_in[10];  // bc1
    wp.p[8] = d_in[11];  // Wc2
    wp.p[9] = d_in[12];  // bc2
    wp.p[10] = d_in[13]; // Wf
    wp.p[11] = d_in[14]; // bf

    // ---- workspace layout (aliased; total ≈ 228 MB) ----
    char* ws = (char*)d_ws;
    size_t o = 0;
    auto take = [&](size_t bytes) { char* r = ws + o; o = (o + bytes + 255) & ~(size_t)255; return r; };
    int*       flags  = (int*)      take(2 * 4);
    float*     wconv  = (float*)    take((size_t)WTOT * 4);
    __bf16*    wt     = (__bf16*)   take((size_t)16384 * 2);
    int*       offs   = (int*)      take((size_t)(NN + 1) * 4);
    long long* epack  = (long long*)take((size_t)(EE + NN) * 8);
    float*     key3   = (float*)    take((size_t)3 * NN * 4);
    int*       topidx = (int*)      take((size_t)BBATCH * KTOP * 4);
    int*       blksum = (int*)      take((size_t)NBLK * 4);
    char*      hbase  = take((size_t)NN * 64 * 4);                   // 52.4 MB, multi-purpose
    float*     feat   = (float*)    take((size_t)NN * 192 * 4);      // 157.3 MB

    float* h      = (float*)hbase;
    // aliases inside h, live only BEFORE first xw kernel:
    int*   cnt    = (int*)(hbase);
    int*   cursor = (int*)(hbase + (1u << 20));
    float* dinv   = (float*)(hbase + (2u << 20));
    // aliases inside h, live only AFTER last spmm_kernel:
    float* pooled = (float*)(hbase);                             // 31.5 MB
    float* pool1  = (float*)(hbase + (34u << 20));               // 6.3 MB

    detect_kernel<<<1, 256, 0, stream>>>((const unsigned int*)x, (const unsigned int*)ei, flags);
    convert_weights_kernel<<<(WTOT + 255) / 256, 256, 0, stream>>>(wp, flags, wconv);
    prep_wt_kernel<<<64, 256, 0, stream>>>(wconv, wt);
    zero_int_kernel<<<NN / 256, 256, 0, stream>>>(cnt, NN);
    count_kernel<<<EE / 256, 256, 0, stream>>>(ei, flags, cnt);
    scan1_kernel<<<NBLK, 1024, 0, stream>>>(cnt, offs, dinv, blksum);
    scan2_kernel<<<1, 256, 0, stream>>>(blksum);
    scan3_kernel<<<NBLK, 1024, 0, stream>>>(offs, blksum);
    fill_self_kernel<<<NN / 256, 256, 0, stream>>>(offs, dinv, cursor, epack);
    fill_edges_kernel<<<EE / 256, 256, 0, stream>>>(ei, flags, offs, dinv, cursor, epack);

    // layer 1 (bf16 path: MFMA; fp32 path: fallback — guards are complementary)
    xw_mfma_kernel<1><<<800, 256, 0, stream>>>(x, flags, 128, 0, wt, h);
    xw_kernel<128, 1><<<NN / 256, 256, 0, stream>>>(x, flags, 128, 0, wconv + OFF_W1, h);
    spmm_kernel<<<NN / 4, 256, 0, stream>>>(h, offs, epack, wconv + OFF_B1, feat, key3);
    // layer 2
    xw_mfma_kernel<0><<<800, 256, 0, stream>>>(feat, flags, 192, 0, wt + 8192, h);
    xw_kernel<64, 0><<<NN / 256, 256, 0, stream>>>(feat, flags, 192, 0, wconv + OFF_W2, h);
    spmm_kernel<<<NN / 4, 256, 0, stream>>>(h, offs, epack, wconv + OFF_B2, feat + 64, key3 + NN);
    // layer 3
    xw_mfma_kernel<0><<<800, 256, 0, stream>>>(feat, flags, 192, 64, wt + 12288, h);
    xw_kernel<64, 0><<<NN / 256, 256, 0, stream>>>(feat, flags, 192, 64, wconv + OFF_W3, h);
    spmm_kernel<<<NN / 4, 256, 0, stream>>>(h, offs, epack, wconv + OFF_B3, feat + 128, key3 + 2 * NN);

    select_topk_kernel<<<BBATCH / 4, 256, 0, stream>>>(key3, topidx);
    sort_gather_kernel<<<BBATCH * KTOP / 4, 256, 0, stream>>>(feat, topidx, pooled);
    conv1_kernel<<<BBATCH, 256, 0, stream>>>(pooled, wconv, pool1);
    conv2_fc_kernel<<<BBATCH, 256, 0, stream>>>(pool1, wconv, flags, d_out);
}

// Round 4
// 879.361 us; speedup vs baseline: 1.2228x; 1.2228x over previous
//
#include <hip/hip_runtime.h>
#include <hip/hip_bf16.h>

#define NN 204800      // nodes
#define EE 1638400     // edges
#define BBATCH 4096    // graphs
#define NPGRAPH 50
#define KTOP 10
#define NBLK 200       // scan blocks (NN / 1024)

// converted-weight offsets (floats) inside wconv region
#define OFF_W1  0
#define OFF_W2  8192
#define OFF_W3  12288
#define OFF_B1  16384
#define OFF_B2  16448
#define OFF_B3  16512
#define OFF_WC1 16576
#define OFF_BC1 17856
#define OFF_WC2 17888
#define OFF_BC2 24032
#define OFF_WF  24096
#define OFF_BF  24736
#define WTOT    24746

__device__ __forceinline__ float bf2f(unsigned short u) {
    unsigned int x = ((unsigned int)u) << 16;
    float f; __builtin_memcpy(&f, &x, 4); return f;
}

// pack (src, coef) into one 8B record: one dirtied line per edge, not two
__device__ __forceinline__ long long pack_sc(int s, float c) {
    return ((long long)(unsigned)__float_as_int(c) << 32) | (unsigned)s;
}

// ---------------- dtype detection ----------------
// flags[0]: 1 if float tensors are fp32, 0 if bf16
// flags[1]: 1 if edge_index is int64, 0 if int32
__global__ void detect_kernel(const unsigned int* __restrict__ xw,
                              const unsigned int* __restrict__ eiw,
                              int* __restrict__ flags) {
    __shared__ int s_f32, s_i64;
    int t = threadIdx.x;
    if (t == 0) { s_f32 = 0; s_i64 = 1; }
    __syncthreads();
    unsigned w = xw[t];                       // 256 words = 512 ushorts of x
    unsigned u0 = w & 0xffffu, u1 = w >> 16;
    int e0 = (u0 >> 7) & 0xff, e1 = (u1 >> 7) & 0xff;
    // genuine bf16 N(0,1) never reaches |v| >= 512 (exp >= 0x88)
    if (e0 >= 0x88 || e1 >= 0x88) atomicOr(&s_f32, 1);
    // int64 indices < 2^31: high word of every packed pair is 0
    if (eiw[2 * t + 1] != 0) atomicAnd(&s_i64, 0);
    __syncthreads();
    if (t == 0) { flags[0] = s_f32; flags[1] = s_i64; }
}

// ---------------- weights convert (bf16 or fp32 -> fp32) ----------------

struct WPtrs { const void* p[12]; };

__global__ void convert_weights_kernel(WPtrs wp, const int* __restrict__ flags,
                                       float* __restrict__ dst) {
    const int lens[12] = {8192,4096,4096,64,64,64,1280,32,6144,64,640,10};
    const int offs[12] = {OFF_W1,OFF_W2,OFF_W3,OFF_B1,OFF_B2,OFF_B3,
                          OFF_WC1,OFF_BC1,OFF_WC2,OFF_BC2,OFF_WF,OFF_BF};
    int f32 = flags[0];
    int t = blockIdx.x * 256 + threadIdx.x;
    for (int s = 0; s < 12; ++s) {
        if (t < lens[s]) {
            float v = f32 ? ((const float*)wp.p[s])[t]
                          : bf2f(((const unsigned short*)wp.p[s])[t]);
            dst[offs[s] + t] = v;
            return;
        }
        t -= lens[s];
    }
}

// ---------------- CSR build ----------------

__global__ void zero_int_kernel(int* p, int n) {
    int i = blockIdx.x * 256 + threadIdx.x;
    if (i < n) p[i] = 0;
}

__device__ __forceinline__ int ld_idx(const void* ei, int i64, long pos) {
    return i64 ? (int)((const long long*)ei)[pos] : ((const int*)ei)[pos];
}

__global__ void count_kernel(const void* __restrict__ ei, const int* __restrict__ flags,
                             int* __restrict__ cnt) {
    int e = blockIdx.x * 256 + threadIdx.x;
    if (e >= EE) return;
    int c = ld_idx(ei, flags[1], (long)EE + e);
    atomicAdd(&cnt[c], 1);
}

// pass 1: block-local exclusive scan of (cnt[i]+1); per-block totals; dinv
__global__ __launch_bounds__(1024) void scan1_kernel(const int* __restrict__ cnt,
                                                     int* __restrict__ offs,
                                                     float* __restrict__ dinv,
                                                     int* __restrict__ blksum) {
    __shared__ int wsum[16];
    int b = blockIdx.x, t = threadIdx.x;
    int lane = t & 63, wid = t >> 6;
    int i = b * 1024 + t;
    int v = cnt[i] + 1;
    int x = v;
    #pragma unroll
    for (int d = 1; d < 64; d <<= 1) { int y = __shfl_up(x, d, 64); if (lane >= d) x += y; }
    if (lane == 63) wsum[wid] = x;
    __syncthreads();
    if (t == 0) {
        int run = 0;
        #pragma unroll
        for (int k = 0; k < 16; ++k) { int tmp = wsum[k]; wsum[k] = run; run += tmp; }
        blksum[b] = run;
    }
    __syncthreads();
    offs[i] = wsum[wid] + x - v;                 // block-local exclusive
    dinv[i] = (float)(1.0 / sqrt((double)v));    // deg = indeg + 1
}

// pass 2: exclusive scan of the 200 block sums (single block)
__global__ __launch_bounds__(256) void scan2_kernel(int* __restrict__ blksum) {
    __shared__ int wsum[4];
    int t = threadIdx.x, lane = t & 63, wid = t >> 6;
    int v = (t < NBLK) ? blksum[t] : 0;
    int x = v;
    #pragma unroll
    for (int d = 1; d < 64; d <<= 1) { int y = __shfl_up(x, d, 64); if (lane >= d) x += y; }
    if (lane == 63) wsum[wid] = x;
    __syncthreads();
    int pre = 0;
    for (int k = 0; k < wid; ++k) pre += wsum[k];
    if (t < NBLK) blksum[t] = pre + x - v;       // exclusive
}

// pass 3: add block offsets; write sentinel
__global__ __launch_bounds__(1024) void scan3_kernel(int* __restrict__ offs,
                                                     const int* __restrict__ blksum) {
    int b = blockIdx.x, i = b * 1024 + threadIdx.x;
    offs[i] += blksum[b];
    if (i == 0) offs[NN] = EE + NN;
}

__global__ void fill_self_kernel(const int* __restrict__ offs, const float* __restrict__ dinv,
                                 int* __restrict__ cursor, long long* __restrict__ epack) {
    int n = blockIdx.x * 256 + threadIdx.x;
    if (n >= NN) return;
    int p = offs[n];
    float d = dinv[n];
    __builtin_nontemporal_store(pack_sc(n, d * d), &epack[p]);
    cursor[n] = 1;
}

__global__ void fill_edges_kernel(const void* __restrict__ ei, const int* __restrict__ flags,
                                  const int* __restrict__ offs,
                                  const float* __restrict__ dinv, int* __restrict__ cursor,
                                  long long* __restrict__ epack) {
    int e = blockIdx.x * 256 + threadIdx.x;
    if (e >= EE) return;
    int i64 = flags[1];
    int r = ld_idx(ei, i64, e);
    int c = ld_idx(ei, i64, (long)EE + e);
    int p = offs[c] + atomicAdd(&cursor[c], 1);
    __builtin_nontemporal_store(pack_sc(r, dinv[r] * dinv[c]), &epack[p]);
}

// ---------------- dense XW (h = X @ W), fp32 acc ----------------
// v2: 128 rows x 2 col-groups per 256-thread block (acc[32]/thread), grid 1600.
// float4 staging, double-buffered LDS (1 barrier per 32-k chunk), odd-stride 33.
// FMA chain per output is k-ascending, identical to v1 -> bit-exact results.
// W row reads are wave-uniform (readfirstlane'd col-group) -> scalar loads.
// MODE 0: input is internal fp32. MODE 1: input dtype from flags[0].

template<int KD, int MODE>
__global__ __launch_bounds__(256) void xw_kernel(const void* __restrict__ xin_,
                                                 const int* __restrict__ flags,
                                                 int row_stride, int col_off,
                                                 const float* __restrict__ W,
                                                 float* __restrict__ hout) {
    __shared__ float xs[2][128 * 33];
    const int t = threadIdx.x;
    const int row = t & 127;                      // row within block
    const int cgs = __builtin_amdgcn_readfirstlane(t >> 7);  // wave-uniform col group
    const long row0 = (long)blockIdx.x * 128;
    const bool bf16in = (MODE == 1) && (flags[0] == 0);

    float acc[32];
    #pragma unroll
    for (int c = 0; c < 32; ++c) acc[c] = 0.f;

    if (bf16in) {
        // rare path: bf16 external input, single-buffer staging (stride 66 ushorts)
        const unsigned short* xg = (const unsigned short*)xin_;
        unsigned short* xsh = (unsigned short*)&xs[0][0];
        for (int kb = 0; kb < KD; kb += 32) {
            __syncthreads();
            #pragma unroll
            for (int u = 0; u < 16; ++u) {
                int idx = u * 256 + t;            // 128 rows x 32 k ushorts
                int r = idx >> 5, k = idx & 31;
                xsh[r * 66 + k] = xg[(row0 + r) * row_stride + col_off + kb + k];
            }
            __syncthreads();
            const unsigned short* xrow = xsh + row * 66;
            const float* wb = W + (long)kb * 64 + cgs * 32;
            #pragma unroll 2
            for (int k = 0; k < 32; ++k) {
                float xk = bf2f(xrow[k]);
                const float* wr = wb + (long)k * 64;
                #pragma unroll
                for (int c = 0; c < 32; ++c) acc[c] = fmaf(xk, wr[c], acc[c]);
            }
        }
    } else {
        const float* xg = (const float*)xin_;
        float4 rg[4];
        #pragma unroll
        for (int u = 0; u < 4; ++u) {             // prefetch chunk 0
            int f4 = u * 256 + t;                 // 128 rows x 8 float4
            int r = f4 >> 3, k4 = f4 & 7;
            rg[u] = *(const float4*)(xg + (row0 + r) * row_stride + col_off + k4 * 4);
        }
        int cur = 0;
        for (int kb = 0; kb < KD; kb += 32) {
            #pragma unroll
            for (int u = 0; u < 4; ++u) {         // regs -> LDS[cur]
                int f4 = u * 256 + t;
                int r = f4 >> 3, k4 = f4 & 7;
                float* d = &xs[cur][r * 33 + k4 * 4];
                d[0] = rg[u].x; d[1] = rg[u].y; d[2] = rg[u].z; d[3] = rg[u].w;
            }
            if (kb + 32 < KD) {
                #pragma unroll
                for (int u = 0; u < 4; ++u) {     // prefetch next chunk
                    int f4 = u * 256 + t;
                    int r = f4 >> 3, k4 = f4 & 7;
                    rg[u] = *(const float4*)(xg + (row0 + r) * row_stride + col_off + kb + 32 + k4 * 4);
                }
            }
            __syncthreads();
            const float* xrow = &xs[cur][row * 33];
            const float* wb = W + (long)kb * 64 + cgs * 32;
            #pragma unroll 2
            for (int k = 0; k < 32; ++k) {
                float xk = xrow[k];
                const float* wr = wb + (long)k * 64;
                #pragma unroll
                for (int c = 0; c < 32; ++c) acc[c] = fmaf(xk, wr[c], acc[c]);
            }
            cur ^= 1;
        }
    }

    float* o = hout + (row0 + row) * 64 + cgs * 32;
    #pragma unroll
    for (int c = 0; c < 32; c += 4) {
        float4 v; v.x = acc[c]; v.y = acc[c+1]; v.z = acc[c+2]; v.w = acc[c+3];
        *(float4*)(o + c) = v;
    }
}

// ---------------- SpMM (+self) + bias + tanh + per-layer key max ----------------
// one wave per node; lane = feature.

__global__ __launch_bounds__(256) void spmm_kernel(const float* __restrict__ h,
                                                   const int* __restrict__ offs,
                                                   const long long* __restrict__ epack,
                                                   const float* __restrict__ bias,
                                                   float* __restrict__ featOut,
                                                   float* __restrict__ keyOut) {
    int node = blockIdx.x * 4 + (threadIdx.x >> 6);
    int lane = threadIdx.x & 63;
    int j0 = offs[node], j1 = offs[node + 1];
    float acc = 0.f;

    for (int base = j0; base < j1; base += 64) {
        int n = j1 - base; if (n > 64) n = 64;
        long long my = 0;
        if (lane < n) my = epack[base + lane];   // coalesced 512B wave load

        int m = 0;
        for (; m + 8 <= n; m += 8) {
            float hv[8], cf[8];
            #pragma unroll
            for (int u = 0; u < 8; ++u) {
                long long e = __shfl(my, m + u, 64);
                int s = (int)(unsigned)e;
                cf[u] = __int_as_float((int)(e >> 32));
                hv[u] = h[(long)s * 64 + lane];
            }
            #pragma unroll
            for (int u = 0; u < 8; ++u) acc = fmaf(hv[u], cf[u], acc);
        }
        for (; m < n; ++m) {
            long long e = __shfl(my, m, 64);
            int s = (int)(unsigned)e;
            float cf = __int_as_float((int)(e >> 32));
            acc = fmaf(h[(long)s * 64 + lane], cf, acc);
        }
    }

    float val = tanhf(acc + bias[lane]);
    featOut[(long)node * 192 + lane] = val;
    float m = val;
    #pragma unroll
    for (int d = 32; d; d >>= 1) m = fmaxf(m, __shfl_xor(m, d, 64));
    if (lane == 0) keyOut[node] = m;
}

// ---------------- top-k selection per graph (key desc, index asc) ----------------

__global__ __launch_bounds__(256) void select_topk_kernel(const float* __restrict__ key3,
                                                          int* __restrict__ topidx) {
    int g = blockIdx.x * 4 + (threadIdx.x >> 6);
    int lane = threadIdx.x & 63;
    int node = g * NPGRAPH + lane;
    float k = -INFINITY;
    if (lane < NPGRAPH)
        k = fmaxf(fmaxf(key3[node], key3[NN + node]), key3[2 * NN + node]);
    for (int r = 0; r < KTOP; ++r) {
        float bk = k; int bi = lane;
        #pragma unroll
        for (int d = 32; d; d >>= 1) {
            float ok = __shfl_xor(bk, d, 64);
            int   oi = __shfl_xor(bi, d, 64);
            if (ok > bk || (ok == bk && oi < bi)) { bk = ok; bi = oi; }
        }
        if (lane == 0) topidx[g * KTOP + r] = g * NPGRAPH + bi;
        if (lane == bi) k = -INFINITY;
    }
}

// ---------------- gather + bitonic sort (values only) ----------------

__global__ __launch_bounds__(256) void sort_gather_kernel(const float* __restrict__ feat,
                                                          const int* __restrict__ topidx,
                                                          float* __restrict__ pooled) {
    int lane = threadIdx.x & 63;
    int w = threadIdx.x >> 6;
    int slot = blockIdx.x * 4 + w;
    int node = topidx[slot];

    unsigned v[4];
    #pragma unroll
    for (int t = 0; t < 3; ++t) {
        float x = feat[(long)node * 192 + 64 * t + lane];
        unsigned u = __float_as_uint(x);
        v[t] = (u & 0x80000000u) ? ~u : (u | 0x80000000u);   // order-preserving key
    }
    v[3] = 0xFF800000u;   // key(+inf) pad

    // bitonic sort, element index e = 64*t + lane, ascending
    #pragma unroll
    for (int k = 2; k <= 256; k <<= 1) {
        #pragma unroll
        for (int d = 128; d >= 1; d >>= 1) {
            if (d >= k) continue;           // folds at compile time
            if (d >= 64) {
                int dt = d >> 6;
                #pragma unroll
                for (int t = 0; t < 4; ++t) {
                    if (!(t & dt)) {
                        int t2 = t | dt;
                        bool asc = ((64 * t) & k) == 0;
                        unsigned a = v[t], b = v[t2];
                        unsigned mn = a < b ? a : b;
                        unsigned mx = a < b ? b : a;
                        v[t]  = asc ? mn : mx;
                        v[t2] = asc ? mx : mn;
                    }
                }
            } else {
                #pragma unroll
                for (int t = 0; t < 4; ++t) {
                    unsigned p = (unsigned)__shfl_xor((int)v[t], d, 64);
                    int e = 64 * t + lane;
                    bool lower = (lane & d) == 0;
                    bool asc = (e & k) == 0;
                    unsigned mn = v[t] < p ? v[t] : p;
                    unsigned mx = v[t] < p ? p : v[t];
                    v[t] = (lower == asc) ? mn : mx;
                }
            }
        }
    }

    #pragma unroll
    for (int t = 0; t < 3; ++t) {
        unsigned kk = v[t];
        unsigned u = (kk & 0x80000000u) ? (kk ^ 0x80000000u) : ~kk;
        pooled[(long)slot * 192 + 64 * t + lane] = __uint_as_float(u);
    }
}

// ---------------- conv1 + relu + maxpool ----------------

__global__ __launch_bounds__(256) void conv1_kernel(const float* __restrict__ pooled,
                                                    const float* __restrict__ wc,
                                                    float* __restrict__ pool1) {
    __shared__ float p[1920];    // [10][192]
    __shared__ float w[1280];    // [32][10][4]
    __shared__ float c1[1536];   // [32][48]
    int b = blockIdx.x, t = threadIdx.x;
    for (int i = t; i < 1920; i += 256) p[i] = pooled[(long)b * 1920 + i];
    for (int i = t; i < 1280; i += 256) w[i] = wc[OFF_WC1 + i];
    __syncthreads();
    for (int o = t; o < 1536; o += 256) {
        int oc = o / 48, s = o % 48;
        float acc = wc[OFF_BC1 + oc];
        #pragma unroll
        for (int ic = 0; ic < 10; ++ic)
            #pragma unroll
            for (int t4 = 0; t4 < 4; ++t4)
                acc = fmaf(p[ic * 192 + s * 4 + t4], w[oc * 40 + ic * 4 + t4], acc);
        c1[o] = fmaxf(acc, 0.f);
    }
    __syncthreads();
    for (int o = t; o < 384; o += 256) {
        int oc = o / 12, q = o % 12;
        float m = c1[oc * 48 + q * 4];
        #pragma unroll
        for (int u = 1; u < 4; ++u) m = fmaxf(m, c1[oc * 48 + q * 4 + u]);
        pool1[(long)b * 384 + o] = m;
    }
}

// ---------------- conv2 + relu + maxpool + FC; out dtype per flags[0] ----------------

__global__ __launch_bounds__(256) void conv2_fc_kernel(const float* __restrict__ pool1,
                                                       const float* __restrict__ wc,
                                                       const int* __restrict__ flags,
                                                       void* __restrict__ outv) {
    __shared__ float p[384];     // [32][12]
    __shared__ float w2[6144];   // [64][32][3]
    __shared__ float r2[256];    // [64][4]
    __shared__ float xfs[64];
    int b = blockIdx.x, t = threadIdx.x;
    int f32o = flags[0];
    for (int i = t; i < 384; i += 256) p[i] = pool1[(long)b * 384 + i];
    for (int i = t; i < 6144; i += 256) w2[i] = wc[OFF_WC2 + i];
    __syncthreads();
    {
        int oc = t >> 2, s = t & 3;
        float acc = wc[OFF_BC2 + oc];
        #pragma unroll
        for (int ic = 0; ic < 32; ++ic)
            #pragma unroll
            for (int t3 = 0; t3 < 3; ++t3)
                acc = fmaf(p[ic * 12 + 3 * s + t3], w2[oc * 96 + ic * 3 + t3], acc);
        r2[t] = fmaxf(acc, 0.f);
    }
    __syncthreads();
    if (t < 64) {
        float m = fmaxf(fmaxf(r2[4*t], r2[4*t+1]), fmaxf(r2[4*t+2], r2[4*t+3]));
        xfs[t] = m;
        long idx = (long)BBATCH * 10 + (long)b * 64 + t;
        if (f32o) ((float*)outv)[idx] = m;
        else      ((__hip_bfloat16*)outv)[idx] = __float2bfloat16(m);
    }
    __syncthreads();
    if (t < 10) {
        float acc = wc[OFF_BF + t];
        #pragma unroll
        for (int o = 0; o < 64; ++o)
            acc = fmaf(fmaxf(xfs[o], 0.f), wc[OFF_WF + o * 10 + t], acc);
        long idx = (long)b * 10 + t;
        if (f32o) ((float*)outv)[idx] = acc;
        else      ((__hip_bfloat16*)outv)[idx] = __float2bfloat16(acc);
    }
}

// ---------------- host ----------------

extern "C" void kernel_launch(void* const* d_in, const int* in_sizes, int n_in,
                              void* d_out, int out_size, void* d_ws, size_t ws_size,
                              hipStream_t stream) {
    const void* x  = d_in[0];   // [N,128] bf16 or fp32 (detected)
    const void* ei = d_in[1];   // [2,E] int32 or int64 (detected)
    // d_in[2] = batch (structure implied, unused)
    WPtrs wp;
    wp.p[0] = d_in[3];   // W1
    wp.p[1] = d_in[5];   // W2
    wp.p[2] = d_in[7];   // W3
    wp.p[3] = d_in[4];   // b1
    wp.p[4] = d_in[6];   // b2
    wp.p[5] = d_in[8];   // b3
    wp.p[6] = d_in[9];   // Wc1
    wp.p[7] = d_in[10];  // bc1
    wp.p[8] = d_in[11];  // Wc2
    wp.p[9] = d_in[12];  // bc2
    wp.p[10] = d_in[13]; // Wf
    wp.p[11] = d_in[14]; // bf

    // ---- workspace layout (aliased; total ≈ 228 MB) ----
    char* ws = (char*)d_ws;
    size_t o = 0;
    auto take = [&](size_t bytes) { char* r = ws + o; o = (o + bytes + 255) & ~(size_t)255; return r; };
    int*       flags  = (int*)      take(2 * 4);
    float*     wconv  = (float*)    take((size_t)WTOT * 4);
    int*       offs   = (int*)      take((size_t)(NN + 1) * 4);
    long long* epack  = (long long*)take((size_t)(EE + NN) * 8);
    float*     key3   = (float*)    take((size_t)3 * NN * 4);
    int*       topidx = (int*)      take((size_t)BBATCH * KTOP * 4);
    int*       blksum = (int*)      take((size_t)NBLK * 4);
    char*      hbase  = take((size_t)NN * 64 * 4);                   // 52.4 MB, multi-purpose
    float*     feat   = (float*)    take((size_t)NN * 192 * 4);      // 157.3 MB

    float* h      = (float*)hbase;
    // aliases inside h, live only BEFORE first xw_kernel:
    int*   cnt    = (int*)(hbase);
    int*   cursor = (int*)(hbase + (1u << 20));
    float* dinv   = (float*)(hbase + (2u << 20));
    // aliases inside h, live only AFTER last spmm_kernel:
    float* pooled = (float*)(hbase);                             // 31.5 MB
    float* pool1  = (float*)(hbase + (34u << 20));               // 6.3 MB

    detect_kernel<<<1, 256, 0, stream>>>((const unsigned int*)x, (const unsigned int*)ei, flags);
    convert_weights_kernel<<<(WTOT + 255) / 256, 256, 0, stream>>>(wp, flags, wconv);
    zero_int_kernel<<<NN / 256, 256, 0, stream>>>(cnt, NN);
    count_kernel<<<EE / 256, 256, 0, stream>>>(ei, flags, cnt);
    scan1_kernel<<<NBLK, 1024, 0, stream>>>(cnt, offs, dinv, blksum);
    scan2_kernel<<<1, 256, 0, stream>>>(blksum);
    scan3_kernel<<<NBLK, 1024, 0, stream>>>(offs, blksum);
    fill_self_kernel<<<NN / 256, 256, 0, stream>>>(offs, dinv, cursor, epack);
    fill_edges_kernel<<<EE / 256, 256, 0, stream>>>(ei, flags, offs, dinv, cursor, epack);

    // layer 1
    xw_kernel<128, 1><<<NN / 128, 256, 0, stream>>>(x, flags, 128, 0, wconv + OFF_W1, h);
    spmm_kernel<<<NN / 4, 256, 0, stream>>>(h, offs, epack, wconv + OFF_B1, feat, key3);
    // layer 2
    xw_kernel<64, 0><<<NN / 128, 256, 0, stream>>>(feat, flags, 192, 0, wconv + OFF_W2, h);
    spmm_kernel<<<NN / 4, 256, 0, stream>>>(h, offs, epack, wconv + OFF_B2, feat + 64, key3 + NN);
    // layer 3
    xw_kernel<64, 0><<<NN / 128, 256, 0, stream>>>(feat, flags, 192, 64, wconv + OFF_W3, h);
    spmm_kernel<<<NN / 4, 256, 0, stream>>>(h, offs, epack, wconv + OFF_B3, feat + 128, key3 + 2 * NN);

    select_topk_kernel<<<BBATCH / 4, 256, 0, stream>>>(key3, topidx);
    sort_gather_kernel<<<BBATCH * KTOP / 4, 256, 0, stream>>>(feat, topidx, pooled);
    conv1_kernel<<<BBATCH, 256, 0, stream>>>(pooled, wconv, pool1);
    conv2_fc_kernel<<<BBATCH, 256, 0, stream>>>(pool1, wconv, flags, d_out);
}